// Round 15
// baseline (181.823 us; speedup 1.0000x reference)
//
#include <hip/hip_runtime.h>

// VQ eval: x[131072,64] fp32, w[1024,64] fp32.
// out concat: x_q (8388608 f32) | loss (1 f32) | indices (131072 f32).
//
// R23: k_screen occupancy fix. Static model: per-chunk latency chain ~600cyc
// vs ~270cyc busy/wave -> with only 4 waves/SIMD (4 blocks/CU, LDS-capped by
// the 28672B block incl. 4KB en), pipes sit at 4*270/600 ~ 45% == measured
// VALUBusy 47 / MfmaUtil 29 / Occ 32. R11 dbuf + R19 counted-vmcnt were null
// because they attacked vmem drain, not wave count. Fix: en[1024] OUT of LDS
// (epilogue reads 2 L2-resident floats/thread/chunk, issued at chunk top,
// hidden under MFMA) -> block LDS 24576B -> 6 blocks/CU = 24 waves (+50%).
// __launch_bounds__(256,6) (VGPR cap 85 >> measured 48). Also k_resolve grid
// 256 -> 512 (~900 items -> <=2/block).
//
//   k_prep    : w_ext (frag-ordered bf16 split of -2w) + en[1024] + wT
//               -> d_ws; zero worklist counter + loss accum + done counter.
//   k_screen  : MFMA screen (dbuf B, en-in-C, mantissa-packed fmed3 top-2)
//               -> ids; flagged -> worklist; FUSED gather + SP[b] partial.
//   k_resolve : BLOCK-per-token worklist resolve (np-fp32-replica body,
//               coalesced wT columns) + flagged idxf + x_q rows; last-block
//               loss finalize via device-coherent atomics (R22, passed).
//
// Screen math: K=192 split A_ext=[x_h|x_l|x_h], B_ext=[wm_h|wm_h|wm_l], wm=-2w.
// s = en[j] - 2*dot entirely in MFMA (en in C). Packed argmin: id in low 10
// mantissa bits, top-2 via fmin+fmed3; packing noise <= ~7.6e-6, gap
// distortion <= ~1.6e-5 < MARGIN=3e-5 -> affected tokens flagged -> exact
// recheck. Ties -> flagged -> first-index preserved. A_ext third segment ==
// first -> not stored; afrag[4]/[5] alias afrag[0]/[1].
//
// d_ws layout (float idx): [0,98304) w_ext | [98304,99328) en | [99328] cnt(int)
//   | [99332,+16384) worklist(int) | [131072,196608) wT | [196608,+1024) SP
//   | [197632] LACC(float) | [197633] DONE(int).  ~776 KB.

#define N_TOK   131072
#define DIM     64
#define KCODES  1024
#define MARGIN  3e-5f
#define LOSS_POS ((size_t)8388608)
#define EN_OFF_F 98304
#define CNT_OFF  99328
#define WL_OFF   99332
#define WL_CAP   16384
#define WT_OFF   131072
#define SP_OFF   196608
#define LACC_OFF 197632
#define DONE_OFF 197633

typedef __attribute__((ext_vector_type(8))) short  short8;
typedef __attribute__((ext_vector_type(4))) float  float4v;

__device__ __forceinline__ unsigned bf16rne(float f) {
    unsigned u = __float_as_uint(f);
    return (u + 0x7FFFu + ((u >> 16) & 1u)) >> 16;
}
__device__ __forceinline__ float bf16tof(unsigned h) { return __uint_as_float(h << 16); }

// ---------------- K0: w_ext + en + wT -> ws; zero counters
__global__ __launch_bounds__(256) void k_prep(const float* __restrict__ w,
                                              float* __restrict__ wsf) {
    if (blockIdx.x == 0 && threadIdx.x == 0) {
        ((int*)wsf)[CNT_OFF]  = 0;
        ((int*)wsf)[DONE_OFF] = 0;
        wsf[LACC_OFF] = 0.0f;
    }
    if (blockIdx.x < 96) {
        const int g    = blockIdx.x * 256 + threadIdx.x;   // 0..24575
        const int lane = g & 63;
        const int fs   = g >> 6;                            // c*12 + nt*6 + ks
        const int c = fs / 12, r = fs % 12, nt = r / 6, ks = r % 6;
        const int j    = c * 32 + nt * 16 + (lane & 15);    // 0..1023
        const int quad = lane >> 4;
        const int kk   = ks * 32 + quad * 8;                // 0..184
        const bool hi  = (kk < 128);
        const int k0   = hi ? (kk & 63) : (kk - 128);
        const float4* src = (const float4*)(w + (size_t)j * DIM + k0);
        float4 v0 = src[0], v1 = src[1];
        float f[8] = {-2.0f * v0.x, -2.0f * v0.y, -2.0f * v0.z, -2.0f * v0.w,
                      -2.0f * v1.x, -2.0f * v1.y, -2.0f * v1.z, -2.0f * v1.w};
        unsigned o[4];
#pragma unroll
        for (int p = 0; p < 4; ++p) {
            unsigned h0 = bf16rne(f[2 * p]), h1 = bf16rne(f[2 * p + 1]);
            if (hi) o[p] = h0 | (h1 << 16);
            else {
                unsigned l0 = bf16rne(f[2 * p]     - bf16tof(h0));
                unsigned l1 = bf16rne(f[2 * p + 1] - bf16tof(h1));
                o[p] = l0 | (l1 << 16);
            }
        }
        *(uint4*)((unsigned*)wsf + (size_t)g * 4) = make_uint4(o[0], o[1], o[2], o[3]);
    } else if (blockIdx.x < 100) {
        const int row = (blockIdx.x - 96) * 256 + threadIdx.x;  // 0..1023
        const float* wr = w + (size_t)row * DIM;
        double en = 0.0;
#pragma unroll 8
        for (int k = 0; k < DIM; ++k) { double v = wr[k]; en += v * v; }
        wsf[EN_OFF_F + row] = (float)en;
    } else {
        // wT[k][j] = w[j][k]; write-coalesced (16 consecutive outputs/thread)
        const int g  = (blockIdx.x - 100) * 256 + threadIdx.x;  // 0..4095
        const int ob = g * 16;
        float* wT = wsf + WT_OFF;
#pragma unroll
        for (int m = 0; m < 16; ++m) {
            const int o = ob + m;
            const int j = o & 1023, k = o >> 10;
            wT[o] = w[(size_t)j * DIM + k];
        }
    }
}

// ---------------- K1: MFMA screen + top-2 + worklist + FUSED gather/loss-partial
// LDS = 24576B (2 x 12288 B-chunk buffers; en NOT staged) -> 6 blocks/CU.
__global__ __launch_bounds__(256, 6) void k_screen(
    const float* __restrict__ x, const float* __restrict__ w,
    float* __restrict__ wsf, float* __restrict__ out,
    float* __restrict__ idxf, int* __restrict__ wsi)
{
    // [0,12288) buf0 | [12288,24576) buf1
    __shared__ __align__(16) unsigned char smem[24576];
    unsigned* smemU = (unsigned*)smem;
    const float* en_g = wsf + EN_OFF_F;   // L2-resident (4KB, shared by all blocks)

    const int tid  = threadIdx.x;
    const int lane = tid & 63;
    const int wv   = tid >> 6;
    const int col  = lane & 15;
    const int quad = (lane >> 4) & 3;
    const int tokBase = blockIdx.x * 128;

    // ---- stage A_ext in two 64-token passes; owning waves grab fragments.
    //      Segments: [0,128)=x_h, [128,256)=x_l; the K=192 third segment == x_h
    //      is NOT stored -- afrag[4]/[5] alias afrag[0]/[1] (identical values).
    short8 afrag[2][6];
    for (int pass = 0; pass < 2; ++pass) {
        const int row = tid >> 2, seg = tid & 3;
        const float4* xr = (const float4*)(x + (size_t)(tokBase + pass * 64 + row) * DIM + seg * 16);
        unsigned* rb = smemU + row * 96 + seg * 8;
#pragma unroll
        for (int q = 0; q < 4; ++q) {
            float4 v = xr[q];
            unsigned hx = bf16rne(v.x), hy = bf16rne(v.y);
            unsigned hz = bf16rne(v.z), hw = bf16rne(v.w);
            unsigned h01 = hx | (hy << 16), h23 = hz | (hw << 16);
            unsigned l01 = bf16rne(v.x - bf16tof(hx)) | (bf16rne(v.y - bf16tof(hy)) << 16);
            unsigned l23 = bf16rne(v.z - bf16tof(hz)) | (bf16rne(v.w - bf16tof(hw)) << 16);
            rb[2 * q] = h01;      rb[2 * q + 1] = h23;        // x_h  (k 0..63)
            rb[32 + 2 * q] = l01; rb[32 + 2 * q + 1] = l23;   // x_l  (k 64..127)
        }
        __syncthreads();
        if ((wv >> 1) == pass) {
#pragma unroll
            for (int mt = 0; mt < 2; ++mt) {
#pragma unroll
                for (int ks = 0; ks < 4; ++ks)
                    afrag[mt][ks] = *(const short8*)(smem
                        + ((wv & 1) * 32 + mt * 16 + col) * 384 + ks * 64 + quad * 16);
                afrag[mt][4] = afrag[mt][0];   // k 128..159 == k 0..31 (x_h)
                afrag[mt][5] = afrag[mt][1];   // k 160..191 == k 32..63 (x_h)
            }
        }
        __syncthreads();   // reads done before region reuse
    }

    // m1/m2 hold PACKED scores: low 10 mantissa bits = code id. m1 <= m2 invariant.
    float m1[8], m2[8];
#pragma unroll
    for (int i = 0; i < 8; ++i) { m1[i] = 3.4e38f; m2[i] = 3.4e38f; }

    // acc initialized to en[j] (chunk 0 columns, from L2); MFMA adds -2*dot.
    float4v acc[2][2];
    {
        const float e0 = en_g[col], e1 = en_g[16 + col];
#pragma unroll
        for (int mt = 0; mt < 2; ++mt) {
            acc[mt][0] = (float4v){e0, e0, e0, e0};
            acc[mt][1] = (float4v){e1, e1, e1, e1};
        }
    }

    const unsigned char* wext = (const unsigned char*)wsf;

    // ---- prologue: stage chunk 0 into buf0
    {
        const unsigned char* gsrc = wext + tid * 16;
        unsigned char*       ldst = smem + tid * 16;
#pragma unroll
        for (int it = 0; it < 3; ++it)
            __builtin_amdgcn_global_load_lds(
                (const __attribute__((address_space(1))) void*)(gsrc + it * 4096),
                (__attribute__((address_space(3))) void*)(ldst + it * 4096),
                16, 0, 0);
    }
    __syncthreads();   // buf0 resident

    for (int c = 0; c < 32; ++c) {
        const int cur = c & 1;
        // next-chunk en (L2) issued early: latency hides under staging+MFMA
        float ecn0 = 0.0f, ecn1 = 0.0f;
        if (c < 31) {
            ecn0 = en_g[(c + 1) * 32 + col];
            ecn1 = en_g[(c + 1) * 32 + 16 + col];
        }
        if (c < 31) {
            const unsigned char* gsrc = wext + (c + 1) * 12288 + tid * 16;
            unsigned char*       ldst = smem + (cur ^ 1) * 12288 + tid * 16;
#pragma unroll
            for (int it = 0; it < 3; ++it)
                __builtin_amdgcn_global_load_lds(
                    (const __attribute__((address_space(1))) void*)(gsrc + it * 4096),
                    (__attribute__((address_space(3))) void*)(ldst + it * 4096),
                    16, 0, 0);
        }

        const unsigned char* bbase = smem + cur * 12288 + (size_t)lane * 16;
#pragma unroll
        for (int ks = 0; ks < 6; ++ks) {
            short8 b0 = *(const short8*)(bbase + (ks)     * 1024);
            short8 b1 = *(const short8*)(bbase + (6 + ks) * 1024);
            acc[0][0] = __builtin_amdgcn_mfma_f32_16x16x32_bf16(afrag[0][ks], b0, acc[0][0], 0, 0, 0);
            acc[1][0] = __builtin_amdgcn_mfma_f32_16x16x32_bf16(afrag[1][ks], b0, acc[1][0], 0, 0, 0);
            acc[0][1] = __builtin_amdgcn_mfma_f32_16x16x32_bf16(afrag[0][ks], b1, acc[0][1], 0, 0, 0);
            acc[1][1] = __builtin_amdgcn_mfma_f32_16x16x32_bf16(afrag[1][ks], b1, acc[1][1], 0, 0, 0);
        }

        {
#pragma unroll
            for (int nt = 0; nt < 2; ++nt) {
                const unsigned jg = (unsigned)(c * 32 + nt * 16 + col);
                const float ecn = nt ? ecn1 : ecn0;
#pragma unroll
                for (int mt = 0; mt < 2; ++mt)
#pragma unroll
                    for (int r = 0; r < 4; ++r) {
                        const int t = mt * 4 + r;
                        float p = __uint_as_float((__float_as_uint(acc[mt][nt][r]) & 0xFFFFFC00u) | jg);
                        m2[t] = __builtin_amdgcn_fmed3f(m1[t], m2[t], p);
                        m1[t] = fminf(m1[t], p);
                        acc[mt][nt][r] = ecn;
                    }
            }
        }
        __syncthreads();
    }

    // ---- merge top-2 across the 16 C/D columns (lane bits 0..3)
#pragma unroll
    for (int m = 1; m <= 8; m <<= 1) {
#pragma unroll
        for (int t = 0; t < 8; ++t) {
            float o1 = __shfl_xor(m1[t], m, 64);
            float o2 = __shfl_xor(m2[t], m, 64);
            m2[t] = fminf(fminf(m2[t], o2), fmaxf(m1[t], o1));
            m1[t] = fminf(m1[t], o1);
        }
    }

    // ---- write ids: idxf (provisional for flagged; k_resolve overwrites),
    //      idxl in LDS (negative = flagged -> gather skips), worklist append.
    float* idxl_s = (float*)smem;              // [0,512)  buf region dead
    double* rr    = (double*)(smem + 1024);    // [1024,3072)
    if (col == 0) {
#pragma unroll
        for (int t = 0; t < 8; ++t) {
            const int mt = t >> 2, r = t & 3;
            const int tokLocal = wv * 32 + mt * 16 + quad * 4 + r;
            const int tok = tokBase + tokLocal;
            const int id  = (int)(__float_as_uint(m1[t]) & 1023u);
            const bool flagged = (m2[t] - m1[t] < MARGIN);
            idxf[tok] = (float)id;
            idxl_s[tokLocal] = flagged ? -(float)(id + 1) : (float)id;
            if (flagged) {
                int p = atomicAdd(wsi + CNT_OFF, 1);
                if (p < WL_CAP) wsi[WL_OFF + p] = tok;
            }
        }
    }
    __syncthreads();

    // ---- fused gather + loss partial for this block's 128 tokens
    //      (flagged skipped; k_resolve writes those rows + their loss)
    {
        const float4* x4 = (const float4*)x;
        const float4* w4 = (const float4*)w;
        float4*       o4 = (float4*)out;
        double lacc = 0.0;
#pragma unroll 4
        for (int kk = 0; kk < 8; ++kk) {
            const int li = tid + kk * 256;          // [0,2048)
            const float fid = idxl_s[li >> 4];
            if (fid >= 0.0f) {
                const int id = (int)fid;
                const size_t gi = (size_t)tokBase * 16 + li;
                float4 xv  = x4[gi];
                float4 wvv = w4[(size_t)id * 16 + (li & 15)];
                o4[gi] = wvv;
                float dx = xv.x - wvv.x, dy = xv.y - wvv.y;
                float dz = xv.z - wvv.z, dw = xv.w - wvv.w;
                lacc += (double)dx * dx + (double)dy * dy + (double)dz * dz + (double)dw * dw;
            }
        }
        rr[tid] = lacc;
        __syncthreads();
        for (int off = 128; off > 0; off >>= 1) {
            if (tid < off) rr[tid] += rr[tid + off];
            __syncthreads();
        }
        if (tid == 0) wsf[SP_OFF + blockIdx.x] = (float)rr[0];
    }
}

// ---------------- K2: worklist resolve + fused loss finalize.
// BLOCK per token: thread t owns codes j = 4t..4t+3 (one wT float4 column):
// 64 coalesced loads/thread, 4 independent fp32 FMA chains (sequential-k,
// bitwise identical per-code math); c-ascending local compare (strict <),
// 256-thread lexicographic (d,j) LDS tree = global first-index argmin.
// Loss finalize (R22, passed): block partial + SP slice -> unsafeAtomicAdd;
// threadfence; DONE counter; last block writes scaled loss.
__global__ __launch_bounds__(256) void k_resolve(
    const float* __restrict__ x, const float* __restrict__ w,
    float* __restrict__ wsf, float* __restrict__ idxf,
    float* __restrict__ out, int* __restrict__ wsi)
{
    __shared__ float  xf[DIM];
    __shared__ float  rd[256];
    __shared__ int    rj[256];
    __shared__ double rl[256];
    const int tid = threadIdx.x;
    int n = wsi[CNT_OFF];
    if (n > WL_CAP) n = WL_CAP;
    const float4* wT4 = (const float4*)(wsf + WT_OFF);   // [64][256] float4
    const float4* en4 = (const float4*)(wsf + EN_OFF_F); // [256] float4
    double lacc = 0.0;

    for (int i = blockIdx.x; i < n; i += gridDim.x) {
        const int ft = wsi[WL_OFF + i];
        if (tid < DIM) xf[tid] = x[(size_t)ft * DIM + tid];
        __syncthreads();

        double xnd = 0.0;
        for (int k = 0; k < DIM; ++k) { double xv = (double)xf[k]; xnd += xv * xv; }
        const float xn = (float)xnd;

        float ca0 = 0.f, ca1 = 0.f, ca2 = 0.f, ca3 = 0.f;
#pragma unroll 8
        for (int k = 0; k < DIM; ++k) {
            float4 wv4 = wT4[k * 256 + tid];    // coalesced: wave reads 1KB row slice
            const float xk = xf[k];
            ca0 = __fmaf_rn(xk, wv4.x, ca0);
            ca1 = __fmaf_rn(xk, wv4.y, ca1);
            ca2 = __fmaf_rn(xk, wv4.z, ca2);
            ca3 = __fmaf_rn(xk, wv4.w, ca3);
        }
        const float4 ev = en4[tid];
        const int jb = tid * 4;
        float d0 = __fsub_rn(__fadd_rn(xn, ev.x), __fmul_rn(2.0f, ca0));
        float d1 = __fsub_rn(__fadd_rn(xn, ev.y), __fmul_rn(2.0f, ca1));
        float d2 = __fsub_rn(__fadd_rn(xn, ev.z), __fmul_rn(2.0f, ca2));
        float d3 = __fsub_rn(__fadd_rn(xn, ev.w), __fmul_rn(2.0f, ca3));
        float dbest = d0; int jbest = jb;                 // c ascending, strict <
        if (d1 < dbest) { dbest = d1; jbest = jb + 1; }
        if (d2 < dbest) { dbest = d2; jbest = jb + 2; }
        if (d3 < dbest) { dbest = d3; jbest = jb + 3; }
        rd[tid] = dbest; rj[tid] = jbest;
        __syncthreads();
        for (int off = 128; off > 0; off >>= 1) {
            if (tid < off) {
                float od = rd[tid + off]; int oj = rj[tid + off];
                if (od < rd[tid] || (od == rd[tid] && oj < rj[tid])) {
                    rd[tid] = od; rj[tid] = oj;
                }
            }
            __syncthreads();
        }
        const int jwin = rj[0];
        if (tid == 0) idxf[ft] = (float)jwin;

        // gather this token's row + its loss contribution (threads 0..15)
        if (tid < 16) {
            const float4* x4 = (const float4*)x;
            const float4* w4 = (const float4*)w;
            float4*       o4 = (float4*)out;
            float4 wvv = w4[(size_t)jwin * 16 + tid];
            float4 xv  = x4[(size_t)ft * 16 + tid];
            o4[(size_t)ft * 16 + tid] = wvv;
            float dx = xv.x - wvv.x, dy = xv.y - wvv.y;
            float dz = xv.z - wvv.z, dw = xv.w - wvv.w;
            lacc += (double)dx * dx + (double)dy * dy + (double)dz * dz + (double)dw * dw;
        }
        __syncthreads();   // xf/rd/rj reads done before next item overwrites
    }

    // ---- loss finalize: fold SP slice (2 entries/block at 512 blocks)
    if (tid < 2) lacc += (double)wsf[SP_OFF + blockIdx.x * 2 + tid];
    rl[tid] = lacc;
    __syncthreads();
    for (int off = 128; off > 0; off >>= 1) {
        if (tid < off) rl[tid] += rl[tid + off];
        __syncthreads();
    }
    if (tid == 0) {
        unsafeAtomicAdd(wsf + LACC_OFF, (float)rl[0]);
        __threadfence();                          // LACC add visible before DONE
        int old = atomicAdd(wsi + DONE_OFF, 1);
        if (old == (int)gridDim.x - 1) {          // last block: all adds done
            float tot = unsafeAtomicAdd(wsf + LACC_OFF, 0.0f);  // coherent read
            out[LOSS_POS] = tot * 1.25f / 8388608.0f;
        }
    }
}

extern "C" void kernel_launch(void* const* d_in, const int* in_sizes, int n_in,
                              void* d_out, int out_size, void* d_ws, size_t ws_size,
                              hipStream_t stream) {
    const float* x = (const float*)d_in[0];
    const float* w = (const float*)d_in[1];
    float* out = (float*)d_out;
    float* idxf = out + LOSS_POS + 1;
    float* wsf  = (float*)d_ws;
    int*   wsi  = (int*)d_ws;

    k_prep<<<116, 256, 0, stream>>>(w, wsf);
    k_screen<<<N_TOK / 128, 256, 0, stream>>>(x, w, wsf, out, idxf, wsi);
    k_resolve<<<512, 256, 0, stream>>>(x, w, wsf, idxf, out, wsi);
}

// Round 16
// 164.480 us; speedup vs baseline: 1.1054x; 1.1054x over previous
//
#include <hip/hip_runtime.h>

// VQ eval: x[131072,64] fp32, w[1024,64] fp32.
// out concat: x_q (8388608 f32) | loss (1 f32) | indices (131072 f32).
//
// R24 = revert to the best-measured configuration (R17/R18, 165.5us).
// Lever ledger for k_screen (all closed by experiment):
//   - software pipelining: R11 dbuf 0-delta; R19 3-deep counted vmcnt 0-delta
//   - occupancy: R9 (256,5)+28KB LDS -> spill, -60us; R23 en-evict +(256,6)
//     -> VGPR cap 85 < ~64+ live -> ~40B/thread scratch (FETCH/WRITE +10MB),
//     -18us; grid=1024 blocks caps at 4/CU regardless (R9 lesson)
//   - fusion: R12 (k_fix) -85us tail; R20/R21 cooperative: deterministic
//     idx corruption (unexplained, 2x) -> abandoned; R22 k_loss-fold -3.6us
//   - launch gaps: R22 isolates per-launch marginal cost ~0; the ~50-60us
//     unaccounted in totals is fixed harness overhead (34MB out memset +
//     reset dispatches), not kernel-addressable.
//
//   k_prep    : w_ext (frag-ordered bf16 split of -2w) + en[1024] + wT
//               -> d_ws; zero worklist counter.
//   k_screen  : MFMA screen (dbuf B, en-in-C, mantissa-packed fmed3 top-2)
//               -> ids; flagged -> worklist; FUSED gather + SP[b] partial.
//   k_resolve : BLOCK-per-token worklist resolve (np-fp32-replica body,
//               coalesced wT columns) + flagged idxf + x_q rows + RP partial.
//   k_loss    : reduce SP[1024] + RP[256] partials (double) + scale.
//
// Screen math: K=192 split A_ext=[x_h|x_l|x_h], B_ext=[wm_h|wm_h|wm_l], wm=-2w.
// s = en[j] - 2*dot entirely in MFMA (en in C). Packed argmin: id in low 10
// mantissa bits, top-2 via fmin+fmed3; packing noise <= ~7.6e-6, gap
// distortion <= ~1.6e-5 < MARGIN=3e-5 -> affected tokens flagged -> exact
// recheck. Ties -> flagged -> first-index preserved. A_ext third segment ==
// first -> not stored; afrag[4]/[5] alias afrag[0]/[1].
//
// d_ws layout (float idx): [0,98304) w_ext | [98304,99328) en | [99328] cnt(int)
//   | [99332,+16384) worklist(int) | [131072,196608) wT | [196608,+1024) SP
//   | [197632,+256) RP.  ~776 KB.

#define N_TOK   131072
#define DIM     64
#define KCODES  1024
#define MARGIN  3e-5f
#define LOSS_POS ((size_t)8388608)
#define EN_OFF_F 98304
#define CNT_OFF  99328
#define WL_OFF   99332
#define WL_CAP   16384
#define WT_OFF   131072
#define SP_OFF   196608
#define RP_OFF   197632

typedef __attribute__((ext_vector_type(8))) short  short8;
typedef __attribute__((ext_vector_type(4))) float  float4v;

__device__ __forceinline__ unsigned bf16rne(float f) {
    unsigned u = __float_as_uint(f);
    return (u + 0x7FFFu + ((u >> 16) & 1u)) >> 16;
}
__device__ __forceinline__ float bf16tof(unsigned h) { return __uint_as_float(h << 16); }

// ---------------- K0: w_ext + en + wT -> ws; zero worklist counter
__global__ __launch_bounds__(256) void k_prep(const float* __restrict__ w,
                                              float* __restrict__ wsf) {
    if (blockIdx.x == 0 && threadIdx.x == 0) ((int*)wsf)[CNT_OFF] = 0;
    if (blockIdx.x < 96) {
        const int g    = blockIdx.x * 256 + threadIdx.x;   // 0..24575
        const int lane = g & 63;
        const int fs   = g >> 6;                            // c*12 + nt*6 + ks
        const int c = fs / 12, r = fs % 12, nt = r / 6, ks = r % 6;
        const int j    = c * 32 + nt * 16 + (lane & 15);    // 0..1023
        const int quad = lane >> 4;
        const int kk   = ks * 32 + quad * 8;                // 0..184
        const bool hi  = (kk < 128);
        const int k0   = hi ? (kk & 63) : (kk - 128);
        const float4* src = (const float4*)(w + (size_t)j * DIM + k0);
        float4 v0 = src[0], v1 = src[1];
        float f[8] = {-2.0f * v0.x, -2.0f * v0.y, -2.0f * v0.z, -2.0f * v0.w,
                      -2.0f * v1.x, -2.0f * v1.y, -2.0f * v1.z, -2.0f * v1.w};
        unsigned o[4];
#pragma unroll
        for (int p = 0; p < 4; ++p) {
            unsigned h0 = bf16rne(f[2 * p]), h1 = bf16rne(f[2 * p + 1]);
            if (hi) o[p] = h0 | (h1 << 16);
            else {
                unsigned l0 = bf16rne(f[2 * p]     - bf16tof(h0));
                unsigned l1 = bf16rne(f[2 * p + 1] - bf16tof(h1));
                o[p] = l0 | (l1 << 16);
            }
        }
        *(uint4*)((unsigned*)wsf + (size_t)g * 4) = make_uint4(o[0], o[1], o[2], o[3]);
    } else if (blockIdx.x < 100) {
        const int row = (blockIdx.x - 96) * 256 + threadIdx.x;  // 0..1023
        const float* wr = w + (size_t)row * DIM;
        double en = 0.0;
#pragma unroll 8
        for (int k = 0; k < DIM; ++k) { double v = wr[k]; en += v * v; }
        wsf[EN_OFF_F + row] = (float)en;
    } else {
        // wT[k][j] = w[j][k]; write-coalesced (16 consecutive outputs/thread)
        const int g  = (blockIdx.x - 100) * 256 + threadIdx.x;  // 0..4095
        const int ob = g * 16;
        float* wT = wsf + WT_OFF;
#pragma unroll
        for (int m = 0; m < 16; ++m) {
            const int o = ob + m;
            const int j = o & 1023, k = o >> 10;
            wT[o] = w[(size_t)j * DIM + k];
        }
    }
}

// ---------------- K1: MFMA screen + top-2 + worklist + FUSED gather/loss-partial
__global__ __launch_bounds__(256, 4) void k_screen(
    const float* __restrict__ x, const float* __restrict__ w,
    float* __restrict__ wsf, float* __restrict__ out,
    float* __restrict__ idxf, int* __restrict__ wsi)
{
    // [0,12288) buf0 | [12288,24576) buf1 | [24576,28672) en
    __shared__ __align__(16) unsigned char smem[28672];
    unsigned* smemU = (unsigned*)smem;
    const float* en_s = (const float*)(smem + 24576);

    const int tid  = threadIdx.x;
    const int lane = tid & 63;
    const int wv   = tid >> 6;
    const int col  = lane & 15;
    const int quad = (lane >> 4) & 3;
    const int tokBase = blockIdx.x * 128;

    // ---- stage en[1024] once (resident for the whole kernel)
    __builtin_amdgcn_global_load_lds(
        (const __attribute__((address_space(1))) void*)
            ((const unsigned char*)(wsf + EN_OFF_F) + tid * 16),
        (__attribute__((address_space(3))) void*)(smem + 24576 + tid * 16),
        16, 0, 0);

    // ---- stage A_ext in two 64-token passes; owning waves grab fragments.
    //      Segments: [0,128)=x_h, [128,256)=x_l; the K=192 third segment == x_h
    //      is NOT stored -- afrag[4]/[5] alias afrag[0]/[1] (identical values).
    short8 afrag[2][6];
    for (int pass = 0; pass < 2; ++pass) {
        const int row = tid >> 2, seg = tid & 3;
        const float4* xr = (const float4*)(x + (size_t)(tokBase + pass * 64 + row) * DIM + seg * 16);
        unsigned* rb = smemU + row * 96 + seg * 8;
#pragma unroll
        for (int q = 0; q < 4; ++q) {
            float4 v = xr[q];
            unsigned hx = bf16rne(v.x), hy = bf16rne(v.y);
            unsigned hz = bf16rne(v.z), hw = bf16rne(v.w);
            unsigned h01 = hx | (hy << 16), h23 = hz | (hw << 16);
            unsigned l01 = bf16rne(v.x - bf16tof(hx)) | (bf16rne(v.y - bf16tof(hy)) << 16);
            unsigned l23 = bf16rne(v.z - bf16tof(hz)) | (bf16rne(v.w - bf16tof(hw)) << 16);
            rb[2 * q] = h01;      rb[2 * q + 1] = h23;        // x_h  (k 0..63)
            rb[32 + 2 * q] = l01; rb[32 + 2 * q + 1] = l23;   // x_l  (k 64..127)
        }
        __syncthreads();
        if ((wv >> 1) == pass) {
#pragma unroll
            for (int mt = 0; mt < 2; ++mt) {
#pragma unroll
                for (int ks = 0; ks < 4; ++ks)
                    afrag[mt][ks] = *(const short8*)(smem
                        + ((wv & 1) * 32 + mt * 16 + col) * 384 + ks * 64 + quad * 16);
                afrag[mt][4] = afrag[mt][0];   // k 128..159 == k 0..31 (x_h)
                afrag[mt][5] = afrag[mt][1];   // k 160..191 == k 32..63 (x_h)
            }
        }
        __syncthreads();   // reads done before region reuse
    }

    // m1/m2 hold PACKED scores: low 10 mantissa bits = code id. m1 <= m2 invariant.
    float m1[8], m2[8];
#pragma unroll
    for (int i = 0; i < 8; ++i) { m1[i] = 3.4e38f; m2[i] = 3.4e38f; }

    // acc initialized to en[j] (chunk 0 columns); MFMA accumulates -2*dot on top.
    float4v acc[2][2];
    {
        const float e0 = en_s[col], e1 = en_s[16 + col];
#pragma unroll
        for (int mt = 0; mt < 2; ++mt) {
            acc[mt][0] = (float4v){e0, e0, e0, e0};
            acc[mt][1] = (float4v){e1, e1, e1, e1};
        }
    }

    const unsigned char* wext = (const unsigned char*)wsf;

    // ---- prologue: stage chunk 0 into buf0
    {
        const unsigned char* gsrc = wext + tid * 16;
        unsigned char*       ldst = smem + tid * 16;
#pragma unroll
        for (int it = 0; it < 3; ++it)
            __builtin_amdgcn_global_load_lds(
                (const __attribute__((address_space(1))) void*)(gsrc + it * 4096),
                (__attribute__((address_space(3))) void*)(ldst + it * 4096),
                16, 0, 0);
    }
    __syncthreads();   // buf0 resident

    for (int c = 0; c < 32; ++c) {
        const int cur = c & 1;
        if (c < 31) {
            const unsigned char* gsrc = wext + (c + 1) * 12288 + tid * 16;
            unsigned char*       ldst = smem + (cur ^ 1) * 12288 + tid * 16;
#pragma unroll
            for (int it = 0; it < 3; ++it)
                __builtin_amdgcn_global_load_lds(
                    (const __attribute__((address_space(1))) void*)(gsrc + it * 4096),
                    (__attribute__((address_space(3))) void*)(ldst + it * 4096),
                    16, 0, 0);
        }

        const unsigned char* bbase = smem + cur * 12288 + (size_t)lane * 16;
#pragma unroll
        for (int ks = 0; ks < 6; ++ks) {
            short8 b0 = *(const short8*)(bbase + (ks)     * 1024);
            short8 b1 = *(const short8*)(bbase + (6 + ks) * 1024);
            acc[0][0] = __builtin_amdgcn_mfma_f32_16x16x32_bf16(afrag[0][ks], b0, acc[0][0], 0, 0, 0);
            acc[1][0] = __builtin_amdgcn_mfma_f32_16x16x32_bf16(afrag[1][ks], b0, acc[1][0], 0, 0, 0);
            acc[0][1] = __builtin_amdgcn_mfma_f32_16x16x32_bf16(afrag[0][ks], b1, acc[0][1], 0, 0, 0);
            acc[1][1] = __builtin_amdgcn_mfma_f32_16x16x32_bf16(afrag[1][ks], b1, acc[1][1], 0, 0, 0);
        }

        {
            float ecn0 = 0.0f, ecn1 = 0.0f;
            if (c < 31) {
                ecn0 = en_s[(c + 1) * 32 + col];
                ecn1 = en_s[(c + 1) * 32 + 16 + col];
            }
#pragma unroll
            for (int nt = 0; nt < 2; ++nt) {
                const unsigned jg = (unsigned)(c * 32 + nt * 16 + col);
                const float ecn = nt ? ecn1 : ecn0;
#pragma unroll
                for (int mt = 0; mt < 2; ++mt)
#pragma unroll
                    for (int r = 0; r < 4; ++r) {
                        const int t = mt * 4 + r;
                        float p = __uint_as_float((__float_as_uint(acc[mt][nt][r]) & 0xFFFFFC00u) | jg);
                        m2[t] = __builtin_amdgcn_fmed3f(m1[t], m2[t], p);
                        m1[t] = fminf(m1[t], p);
                        acc[mt][nt][r] = ecn;
                    }
            }
        }
        __syncthreads();
    }

    // ---- merge top-2 across the 16 C/D columns (lane bits 0..3)
#pragma unroll
    for (int m = 1; m <= 8; m <<= 1) {
#pragma unroll
        for (int t = 0; t < 8; ++t) {
            float o1 = __shfl_xor(m1[t], m, 64);
            float o2 = __shfl_xor(m2[t], m, 64);
            m2[t] = fminf(fminf(m2[t], o2), fmaxf(m1[t], o1));
            m1[t] = fminf(m1[t], o1);
        }
    }

    // ---- write ids: idxf (provisional for flagged; k_resolve overwrites),
    //      idxl in LDS (negative = flagged -> gather skips), worklist append.
    float* idxl_s = (float*)smem;              // [0,512)  buf region dead
    double* rr    = (double*)(smem + 1024);    // [1024,3072)
    if (col == 0) {
#pragma unroll
        for (int t = 0; t < 8; ++t) {
            const int mt = t >> 2, r = t & 3;
            const int tokLocal = wv * 32 + mt * 16 + quad * 4 + r;
            const int tok = tokBase + tokLocal;
            const int id  = (int)(__float_as_uint(m1[t]) & 1023u);
            const bool flagged = (m2[t] - m1[t] < MARGIN);
            idxf[tok] = (float)id;
            idxl_s[tokLocal] = flagged ? -(float)(id + 1) : (float)id;
            if (flagged) {
                int p = atomicAdd(wsi + CNT_OFF, 1);
                if (p < WL_CAP) wsi[WL_OFF + p] = tok;
            }
        }
    }
    __syncthreads();

    // ---- fused gather + loss partial for this block's 128 tokens
    //      (flagged skipped; k_resolve writes those rows + their loss)
    {
        const float4* x4 = (const float4*)x;
        const float4* w4 = (const float4*)w;
        float4*       o4 = (float4*)out;
        double lacc = 0.0;
#pragma unroll 4
        for (int kk = 0; kk < 8; ++kk) {
            const int li = tid + kk * 256;          // [0,2048)
            const float fid = idxl_s[li >> 4];
            if (fid >= 0.0f) {
                const int id = (int)fid;
                const size_t gi = (size_t)tokBase * 16 + li;
                float4 xv  = x4[gi];
                float4 wvv = w4[(size_t)id * 16 + (li & 15)];
                o4[gi] = wvv;
                float dx = xv.x - wvv.x, dy = xv.y - wvv.y;
                float dz = xv.z - wvv.z, dw = xv.w - wvv.w;
                lacc += (double)dx * dx + (double)dy * dy + (double)dz * dz + (double)dw * dw;
            }
        }
        rr[tid] = lacc;
        __syncthreads();
        for (int off = 128; off > 0; off >>= 1) {
            if (tid < off) rr[tid] += rr[tid + off];
            __syncthreads();
        }
        if (tid == 0) wsf[SP_OFF + blockIdx.x] = (float)rr[0];
    }
}

// ---------------- K2: worklist resolve, BLOCK per token. Thread t owns codes
// j = 4t..4t+3 (one wT float4 column): 64 coalesced loads/thread, 4 independent
// fp32 FMA chains (sequential-k, bitwise identical per-code math); c-ascending
// local compare (strict <), then 256-thread lexicographic (d,j) LDS tree
// (thread-major j order ascending) == global first-index argmin.
__global__ __launch_bounds__(256) void k_resolve(
    const float* __restrict__ x, const float* __restrict__ w,
    float* __restrict__ wsf, float* __restrict__ idxf,
    float* __restrict__ out, const int* __restrict__ wsi)
{
    __shared__ float  xf[DIM];
    __shared__ float  rd[256];
    __shared__ int    rj[256];
    __shared__ double rl[256];
    const int tid = threadIdx.x;
    int n = wsi[CNT_OFF];
    if (n > WL_CAP) n = WL_CAP;
    const float4* wT4 = (const float4*)(wsf + WT_OFF);   // [64][256] float4
    const float4* en4 = (const float4*)(wsf + EN_OFF_F); // [256] float4
    double lacc = 0.0;

    for (int i = blockIdx.x; i < n; i += gridDim.x) {
        const int ft = wsi[WL_OFF + i];
        if (tid < DIM) xf[tid] = x[(size_t)ft * DIM + tid];
        __syncthreads();

        double xnd = 0.0;
        for (int k = 0; k < DIM; ++k) { double xv = (double)xf[k]; xnd += xv * xv; }
        const float xn = (float)xnd;

        float ca0 = 0.f, ca1 = 0.f, ca2 = 0.f, ca3 = 0.f;
#pragma unroll 8
        for (int k = 0; k < DIM; ++k) {
            float4 wv4 = wT4[k * 256 + tid];    // coalesced: wave reads 1KB row slice
            const float xk = xf[k];
            ca0 = __fmaf_rn(xk, wv4.x, ca0);
            ca1 = __fmaf_rn(xk, wv4.y, ca1);
            ca2 = __fmaf_rn(xk, wv4.z, ca2);
            ca3 = __fmaf_rn(xk, wv4.w, ca3);
        }
        const float4 ev = en4[tid];
        const int jb = tid * 4;
        float d0 = __fsub_rn(__fadd_rn(xn, ev.x), __fmul_rn(2.0f, ca0));
        float d1 = __fsub_rn(__fadd_rn(xn, ev.y), __fmul_rn(2.0f, ca1));
        float d2 = __fsub_rn(__fadd_rn(xn, ev.z), __fmul_rn(2.0f, ca2));
        float d3 = __fsub_rn(__fadd_rn(xn, ev.w), __fmul_rn(2.0f, ca3));
        float dbest = d0; int jbest = jb;                 // c ascending, strict <
        if (d1 < dbest) { dbest = d1; jbest = jb + 1; }
        if (d2 < dbest) { dbest = d2; jbest = jb + 2; }
        if (d3 < dbest) { dbest = d3; jbest = jb + 3; }
        rd[tid] = dbest; rj[tid] = jbest;
        __syncthreads();
        for (int off = 128; off > 0; off >>= 1) {
            if (tid < off) {
                float od = rd[tid + off]; int oj = rj[tid + off];
                if (od < rd[tid] || (od == rd[tid] && oj < rj[tid])) {
                    rd[tid] = od; rj[tid] = oj;
                }
            }
            __syncthreads();
        }
        const int jwin = rj[0];
        if (tid == 0) idxf[ft] = (float)jwin;

        // gather this token's row + its loss contribution (threads 0..15)
        if (tid < 16) {
            const float4* x4 = (const float4*)x;
            const float4* w4 = (const float4*)w;
            float4*       o4 = (float4*)out;
            float4 wvv = w4[(size_t)jwin * 16 + tid];
            float4 xv  = x4[(size_t)ft * 16 + tid];
            o4[(size_t)ft * 16 + tid] = wvv;
            float dx = xv.x - wvv.x, dy = xv.y - wvv.y;
            float dz = xv.z - wvv.z, dw = xv.w - wvv.w;
            lacc += (double)dx * dx + (double)dy * dy + (double)dz * dz + (double)dw * dw;
        }
        __syncthreads();   // xf/rd/rj reads done before next item overwrites
    }

    // per-block loss partial (every block writes, 0 if idle)
    rl[tid] = lacc;
    __syncthreads();
    for (int off = 128; off > 0; off >>= 1) {
        if (tid < off) rl[tid] += rl[tid + off];
        __syncthreads();
    }
    if (tid == 0) wsf[RP_OFF + blockIdx.x] = (float)rl[0];
}

// ---------------- K3: reduce SP[1024] + RP[256] partials (double) + scale
__global__ __launch_bounds__(256) void k_loss(const float* __restrict__ wsf,
                                              float* __restrict__ out) {
    __shared__ double r[256];
    const int t = threadIdx.x;
    double s = 0.0;
#pragma unroll
    for (int i = 0; i < 4; ++i) s += (double)wsf[SP_OFF + t + i * 256];
    s += (double)wsf[RP_OFF + t];
    r[t] = s;
    __syncthreads();
    for (int off = 128; off > 0; off >>= 1) {
        if (t < off) r[t] += r[t + off];
        __syncthreads();
    }
    if (t == 0) out[LOSS_POS] = (float)(r[0] * 1.25 / 8388608.0);
}

extern "C" void kernel_launch(void* const* d_in, const int* in_sizes, int n_in,
                              void* d_out, int out_size, void* d_ws, size_t ws_size,
                              hipStream_t stream) {
    const float* x = (const float*)d_in[0];
    const float* w = (const float*)d_in[1];
    float* out = (float*)d_out;
    float* idxf = out + LOSS_POS + 1;
    float* wsf  = (float*)d_ws;
    int*   wsi  = (int*)d_ws;

    k_prep<<<116, 256, 0, stream>>>(w, wsf);
    k_screen<<<N_TOK / 128, 256, 0, stream>>>(x, w, wsf, out, idxf, wsi);
    k_resolve<<<256, 256, 0, stream>>>(x, w, wsf, idxf, out, wsi);
    k_loss<<<1, 256, 0, stream>>>(wsf, out);
}